// Round 10
// baseline (243.912 us; speedup 1.0000x reference)
//
#include <hip/hip_runtime.h>

#define S_LEN 4096
#define NROWS 16384   // B*S
#define PSTR 152      // P-strip row stride (ushorts): 2-way bank aliasing only (free)

typedef __attribute__((ext_vector_type(8))) __bf16 bf16x8;
typedef __attribute__((ext_vector_type(8))) unsigned short ushort8;
typedef __attribute__((ext_vector_type(4))) float floatx4;

__device__ __forceinline__ unsigned short f2bf(float f) {   // RNE
    unsigned int u = __float_as_uint(f);
    unsigned int r = (u + 0x7fffu + ((u >> 16) & 1u)) >> 16;
    return (unsigned short)r;
}

__device__ __forceinline__ float fast_exp2(float x) {       // v_exp_f32 (R6-validated)
    return __builtin_amdgcn_exp2f(x);
}

__device__ __forceinline__ bf16x8 cvt_bf16x8(float4 a, float4 b) {
    union { ushort8 u; bf16x8 v; } r;
    r.u[0] = f2bf(a.x); r.u[1] = f2bf(a.y); r.u[2] = f2bf(a.z); r.u[3] = f2bf(a.w);
    r.u[4] = f2bf(b.x); r.u[5] = f2bf(b.y); r.u[6] = f2bf(b.z); r.u[7] = f2bf(b.w);
    return r.v;
}

// ---------------- K0: weights fp32 -> bf16 transposed (proven)
__global__ __launch_bounds__(256) void convw_kernel(
    const float* __restrict__ Wq, const float* __restrict__ Wk,
    const float* __restrict__ Wv, const float* __restrict__ Wo,
    unsigned short* __restrict__ WqT, unsigned short* __restrict__ WkT,
    unsigned short* __restrict__ WvT, unsigned short* __restrict__ WoT)
{
    int tid = blockIdx.x * 256 + threadIdx.x;   // 0..32767
    int n = tid >> 9, k = tid & 511;            // (n<64, k<512)
    WqT[tid] = f2bf(Wq[k * 64 + n]);
    WkT[tid] = f2bf(Wk[k * 64 + n]);
    WvT[tid] = f2bf(Wv[k * 64 + n]);
    int n2 = tid >> 6, k2 = tid & 63;           // (n2<512, k2<64)
    WoT[tid] = f2bf(Wo[k2 * 512 + n2]);
}

// ---------------- K1: fused QKV projection (proven R2/R8 kernel, unchanged)
__global__ __launch_bounds__(64) void qkv_kernel(
    const float* __restrict__ x,
    const unsigned short* __restrict__ WqT, const unsigned short* __restrict__ WkT,
    const unsigned short* __restrict__ WvT,
    const float* __restrict__ bq, const float* __restrict__ bk, const float* __restrict__ bv,
    unsigned short* __restrict__ Qb, unsigned short* __restrict__ Kb,
    unsigned short* __restrict__ Vt)
{
    const int row0 = blockIdx.x * 16;
    const int lane = threadIdx.x, cl = lane & 15, quad = lane >> 4;
    floatx4 aQ[4], aK[4], aV[4];
    #pragma unroll
    for (int t = 0; t < 4; t++) { aQ[t] = (floatx4){0,0,0,0}; aK[t] = (floatx4){0,0,0,0}; aV[t] = (floatx4){0,0,0,0}; }
    const float* xrow = x + (size_t)(row0 + cl) * 512;
    #pragma unroll 2
    for (int kc = 0; kc < 16; kc++) {
        const int k0 = kc * 32 + quad * 8;
        float4 xa = *(const float4*)(xrow + k0);
        float4 xb = *(const float4*)(xrow + k0 + 4);
        bf16x8 af = cvt_bf16x8(xa, xb);
        #pragma unroll
        for (int t = 0; t < 4; t++) {
            const int widx = (t * 16 + cl) * 512 + k0;
            bf16x8 bQ = *(const bf16x8*)(const void*)(WqT + widx);
            bf16x8 bK = *(const bf16x8*)(const void*)(WkT + widx);
            bf16x8 bV = *(const bf16x8*)(const void*)(WvT + widx);
            aQ[t] = __builtin_amdgcn_mfma_f32_16x16x32_bf16(af, bQ, aQ[t], 0, 0, 0);
            aK[t] = __builtin_amdgcn_mfma_f32_16x16x32_bf16(af, bK, aK[t], 0, 0, 0);
            aV[t] = __builtin_amdgcn_mfma_f32_16x16x32_bf16(af, bV, aV[t], 0, 0, 0);
        }
    }
    const int b = row0 >> 12, s_base = row0 & 4095;
    #pragma unroll
    for (int t = 0; t < 4; t++) {
        const int d = t * 16 + cl;
        const float bqd = bq[d], bkd = bk[d], bvd = bv[d];
        #pragma unroll
        for (int r = 0; r < 4; r++) {
            const int rr = quad * 4 + r;
            Qb[(size_t)(row0 + rr) * 64 + d] = f2bf(aQ[t][r] + bqd);
            Kb[(size_t)(row0 + rr) * 64 + d] = f2bf(aK[t][r] + bkd);
            Vt[((size_t)b * 64 + d) * S_LEN + s_base + rr] = f2bf(aV[t][r] + bvd);
        }
    }
}

// ---------------- K2: causal flash attention, UNIFORM CHUNKED SPLIT-K.
// grid (4,4,256) = (chunk c, batch b, q-tile qt); chunk = 16 key-tiles (1024
// keys); c > qt>>6 exits. Each wave: <=2 R5-proven paired 128-key strips with
// constant-max softmax (R8-proven: scores /sqrt(4096) -> exp2 can't overflow;
// partials merge by plain ADDITION). Block writes unnormalized fp32 partial
// (O 16x64 + l 16) to its chunk slot; oproj reduces.
__global__ __launch_bounds__(256, 2) void attn_kernel(
    const unsigned short* __restrict__ Qb, const unsigned short* __restrict__ Kb,
    const unsigned short* __restrict__ Vt,
    float* __restrict__ Opart, float* __restrict__ lpart)
{
    __shared__ unsigned short Ps[4][16 * PSTR];
    __shared__ float Op[4][16][66];
    __shared__ float Ll[4][16];
    const int c = blockIdx.x, b = blockIdx.y, qt = blockIdx.z;
    const int g = qt >> 6;                   // nc-1
    if (c > g) return;                       // uniform early exit (before any barrier)
    const int q0 = qt * 16;
    const int nkt = (qt >> 2) + 1;           // causal key-tiles
    const int tile0 = c * 16;
    const int tile_end = min(tile0 + 16, nkt);
    const int slot = b * 640 + (g + 1) * (32 * g + (qt & 63)) + c;
    const int tid = threadIdx.x;
    const int w = tid >> 6, lane = tid & 63, cl = lane & 15, quad = lane >> 4;

    const size_t qrow = (size_t)b * S_LEN + q0 + cl;
    const bf16x8 aq0 = *(const bf16x8*)(const void*)(Qb + qrow * 64 + quad * 8);
    const bf16x8 aq1 = *(const bf16x8*)(const void*)(Qb + qrow * 64 + 32 + quad * 8);
    const unsigned short* kbb = Kb + (size_t)b * S_LEN * 64;
    const unsigned short* vbb = Vt + (size_t)b * 64 * S_LEN;

    float lrow[4] = {0.f, 0.f, 0.f, 0.f};
    floatx4 Oacc[4];
    #pragma unroll
    for (int u = 0; u < 4; u++) Oacc[u] = (floatx4){0.f, 0.f, 0.f, 0.f};
    const float C2 = 0.022542110013890054f;  // log2(e)/sqrt(4096)
    unsigned short* Pw = Ps[w];

    int jt = tile0 + w;
    // -------- paired 128-key strips (R5 body, constant max) --------
    for (; jt + 4 < tile_end; jt += 8) {
        const int j0a = jt * 64, j0b = (jt + 4) * 64;
        float z[8][4];
        bf16x8 vf[8][2];
        {
            bf16x8 kf[4][2];
            #pragma unroll
            for (int t = 0; t < 4; t++) {
                const unsigned short* kp = kbb + (size_t)(j0a + t * 16 + cl) * 64 + quad * 8;
                kf[t][0] = *(const bf16x8*)(const void*)kp;
                kf[t][1] = *(const bf16x8*)(const void*)(kp + 32);
            }
            #pragma unroll
            for (int t = 0; t < 4; t++) {
                floatx4 acc = (floatx4){0.f, 0.f, 0.f, 0.f};
                acc = __builtin_amdgcn_mfma_f32_16x16x32_bf16(aq0, kf[t][0], acc, 0, 0, 0);
                acc = __builtin_amdgcn_mfma_f32_16x16x32_bf16(aq1, kf[t][1], acc, 0, 0, 0);
                #pragma unroll
                for (int r = 0; r < 4; r++) z[t][r] = acc[r] * C2;
            }
        }
        #pragma unroll
        for (int u = 0; u < 4; u++) {
            const unsigned short* vp = vbb + (size_t)(u * 16 + cl) * S_LEN + j0a + quad * 8;
            vf[u][0] = *(const bf16x8*)(const void*)vp;
            vf[u][1] = *(const bf16x8*)(const void*)(vp + 32);
        }
        {
            bf16x8 kf[4][2];
            #pragma unroll
            for (int t = 0; t < 4; t++) {
                const unsigned short* kp = kbb + (size_t)(j0b + t * 16 + cl) * 64 + quad * 8;
                kf[t][0] = *(const bf16x8*)(const void*)kp;
                kf[t][1] = *(const bf16x8*)(const void*)(kp + 32);
            }
            #pragma unroll
            for (int t = 0; t < 4; t++) {
                floatx4 acc = (floatx4){0.f, 0.f, 0.f, 0.f};
                acc = __builtin_amdgcn_mfma_f32_16x16x32_bf16(aq0, kf[t][0], acc, 0, 0, 0);
                acc = __builtin_amdgcn_mfma_f32_16x16x32_bf16(aq1, kf[t][1], acc, 0, 0, 0);
                #pragma unroll
                for (int r = 0; r < 4; r++) z[4 + t][r] = acc[r] * C2;
            }
        }
        #pragma unroll
        for (int u = 0; u < 4; u++) {
            const unsigned short* vp = vbb + (size_t)(u * 16 + cl) * S_LEN + j0b + quad * 8;
            vf[4 + u][0] = *(const bf16x8*)(const void*)vp;
            vf[4 + u][1] = *(const bf16x8*)(const void*)(vp + 32);
        }
        if (jt + 4 == nkt - 1) {   // diagonal only possible on pair's 2nd tile
            #pragma unroll
            for (int t = 0; t < 4; t++)
                #pragma unroll
                for (int r = 0; r < 4; r++)
                    if (j0b + t * 16 + cl > q0 + quad * 4 + r) z[4 + t][r] = -1e30f;
        }
        #pragma unroll
        for (int t = 0; t < 8; t++)
            #pragma unroll
            for (int r = 0; r < 4; r++) z[t][r] = fast_exp2(z[t][r]);
        #pragma unroll
        for (int r = 0; r < 4; r++)
            lrow[r] += ((z[0][r] + z[1][r]) + (z[2][r] + z[3][r]))
                     + ((z[4][r] + z[5][r]) + (z[6][r] + z[7][r]));
        #pragma unroll
        for (int t = 0; t < 8; t++)
            #pragma unroll
            for (int r = 0; r < 4; r++)
                Pw[(quad * 4 + r) * PSTR + t * 16 + cl] = f2bf(z[t][r]);
        asm volatile("s_waitcnt lgkmcnt(0)" ::: "memory");
        bf16x8 ap0 = *(const bf16x8*)(const void*)(Pw + cl * PSTR + quad * 8);
        bf16x8 ap1 = *(const bf16x8*)(const void*)(Pw + cl * PSTR + 32 + quad * 8);
        bf16x8 ap2 = *(const bf16x8*)(const void*)(Pw + cl * PSTR + 64 + quad * 8);
        bf16x8 ap3 = *(const bf16x8*)(const void*)(Pw + cl * PSTR + 96 + quad * 8);
        #pragma unroll
        for (int u = 0; u < 4; u++) {
            Oacc[u] = __builtin_amdgcn_mfma_f32_16x16x32_bf16(ap0, vf[u][0], Oacc[u], 0, 0, 0);
            Oacc[u] = __builtin_amdgcn_mfma_f32_16x16x32_bf16(ap1, vf[u][1], Oacc[u], 0, 0, 0);
            Oacc[u] = __builtin_amdgcn_mfma_f32_16x16x32_bf16(ap2, vf[4 + u][0], Oacc[u], 0, 0, 0);
            Oacc[u] = __builtin_amdgcn_mfma_f32_16x16x32_bf16(ap3, vf[4 + u][1], Oacc[u], 0, 0, 0);
        }
    }
    // -------- leftover single tile --------
    if (jt < tile_end) {
        const int j0 = jt * 64;
        bf16x8 kf[4][2], vf[4][2];
        #pragma unroll
        for (int t = 0; t < 4; t++) {
            const unsigned short* kp = kbb + (size_t)(j0 + t * 16 + cl) * 64 + quad * 8;
            kf[t][0] = *(const bf16x8*)(const void*)kp;
            kf[t][1] = *(const bf16x8*)(const void*)(kp + 32);
        }
        #pragma unroll
        for (int u = 0; u < 4; u++) {
            const unsigned short* vp = vbb + (size_t)(u * 16 + cl) * S_LEN + j0 + quad * 8;
            vf[u][0] = *(const bf16x8*)(const void*)vp;
            vf[u][1] = *(const bf16x8*)(const void*)(vp + 32);
        }
        float z[4][4];
        #pragma unroll
        for (int t = 0; t < 4; t++) {
            floatx4 acc = (floatx4){0.f, 0.f, 0.f, 0.f};
            acc = __builtin_amdgcn_mfma_f32_16x16x32_bf16(aq0, kf[t][0], acc, 0, 0, 0);
            acc = __builtin_amdgcn_mfma_f32_16x16x32_bf16(aq1, kf[t][1], acc, 0, 0, 0);
            #pragma unroll
            for (int r = 0; r < 4; r++) z[t][r] = acc[r] * C2;
        }
        if (jt == nkt - 1) {
            #pragma unroll
            for (int t = 0; t < 4; t++)
                #pragma unroll
                for (int r = 0; r < 4; r++)
                    if (j0 + t * 16 + cl > q0 + quad * 4 + r) z[t][r] = -1e30f;
        }
        #pragma unroll
        for (int t = 0; t < 4; t++)
            #pragma unroll
            for (int r = 0; r < 4; r++) z[t][r] = fast_exp2(z[t][r]);
        #pragma unroll
        for (int r = 0; r < 4; r++)
            lrow[r] += (z[0][r] + z[1][r]) + (z[2][r] + z[3][r]);
        #pragma unroll
        for (int t = 0; t < 4; t++)
            #pragma unroll
            for (int r = 0; r < 4; r++)
                Pw[(quad * 4 + r) * PSTR + t * 16 + cl] = f2bf(z[t][r]);
        asm volatile("s_waitcnt lgkmcnt(0)" ::: "memory");
        bf16x8 ap0 = *(const bf16x8*)(const void*)(Pw + cl * PSTR + quad * 8);
        bf16x8 ap1 = *(const bf16x8*)(const void*)(Pw + cl * PSTR + 32 + quad * 8);
        #pragma unroll
        for (int u = 0; u < 4; u++) {
            Oacc[u] = __builtin_amdgcn_mfma_f32_16x16x32_bf16(ap0, vf[u][0], Oacc[u], 0, 0, 0);
            Oacc[u] = __builtin_amdgcn_mfma_f32_16x16x32_bf16(ap1, vf[u][1], Oacc[u], 0, 0, 0);
        }
    }
    // l: reduce over the 16 key-lanes once
    #pragma unroll
    for (int r = 0; r < 4; r++) {
        float s = lrow[r];
        s += __shfl_xor(s, 1, 64);
        s += __shfl_xor(s, 2, 64);
        s += __shfl_xor(s, 4, 64);
        s += __shfl_xor(s, 8, 64);
        lrow[r] = s;
    }
    // publish + block merge (plain sums) + unnormalized partial write
    #pragma unroll
    for (int u = 0; u < 4; u++)
        #pragma unroll
        for (int r = 0; r < 4; r++)
            Op[w][quad * 4 + r][u * 16 + cl] = Oacc[u][r];
    if (cl == 0) {
        #pragma unroll
        for (int r = 0; r < 4; r++) Ll[w][quad * 4 + r] = lrow[r];
    }
    __syncthreads();
    {
        const int row = tid >> 4, d0 = (tid & 15) * 4;
        float4 o;
        o.x = (Op[0][row][d0+0] + Op[1][row][d0+0]) + (Op[2][row][d0+0] + Op[3][row][d0+0]);
        o.y = (Op[0][row][d0+1] + Op[1][row][d0+1]) + (Op[2][row][d0+1] + Op[3][row][d0+1]);
        o.z = (Op[0][row][d0+2] + Op[1][row][d0+2]) + (Op[2][row][d0+2] + Op[3][row][d0+2]);
        o.w = (Op[0][row][d0+3] + Op[1][row][d0+3]) + (Op[2][row][d0+3] + Op[3][row][d0+3]);
        *(float4*)(Opart + (size_t)slot * 1024 + tid * 4) = o;
        if ((tid & 15) == 0)
            lpart[slot * 16 + row] = (Ll[0][row] + Ll[1][row]) + (Ll[2][row] + Ll[3][row]);
    }
}

// ---------------- K3: chunk-reduce + normalize + O @ Wo + bo (fused).
// Block bid <-> q-tile (b = bid>>8, qt = bid&255); rows bid*16..+16.
__global__ __launch_bounds__(256) void oproj_kernel(
    const float* __restrict__ Opart, const float* __restrict__ lpart,
    const unsigned short* __restrict__ WoT, const float* __restrict__ bo,
    float* __restrict__ out)
{
    __shared__ unsigned short Osm[16][68];
    const int bid = blockIdx.x;               // 0..1023
    const int b = bid >> 8, qt = bid & 255;
    const int g = qt >> 6, nc = g + 1;
    const int slot0 = b * 640 + (g + 1) * (32 * g + (qt & 63));
    const int tid = threadIdx.x;
    // reduce nc chunk partials: thread -> 4 consecutive elements
    {
        const int row = tid >> 4, d0 = (tid & 15) * 4;
        float4 acc = {0.f, 0.f, 0.f, 0.f};
        float L = 0.f;
        for (int cc = 0; cc < nc; cc++) {
            const float4 v = *(const float4*)(Opart + (size_t)(slot0 + cc) * 1024 + tid * 4);
            acc.x += v.x; acc.y += v.y; acc.z += v.z; acc.w += v.w;
            L += lpart[(slot0 + cc) * 16 + row];
        }
        const float invL = 1.0f / L;
        unsigned short ov[4];
        ov[0] = f2bf(acc.x * invL); ov[1] = f2bf(acc.y * invL);
        ov[2] = f2bf(acc.z * invL); ov[3] = f2bf(acc.w * invL);
        *(uint2*)(void*)(&Osm[row][d0]) = *(const uint2*)ov;
    }
    __syncthreads();
    const int w = tid >> 6, lane = tid & 63, cl = lane & 15, quad = lane >> 4;
    const bf16x8 a0 = *(const bf16x8*)(const void*)(&Osm[cl][quad * 8]);
    const bf16x8 a1 = *(const bf16x8*)(const void*)(&Osm[cl][32 + quad * 8]);
    const size_t row0 = (size_t)bid * 16;
    #pragma unroll 2
    for (int i = 0; i < 8; i++) {
        const int n = w * 128 + i * 16 + cl;
        const unsigned short* wp = WoT + (size_t)n * 64 + quad * 8;
        bf16x8 b0 = *(const bf16x8*)(const void*)wp;
        bf16x8 b1 = *(const bf16x8*)(const void*)(wp + 32);
        floatx4 acc = (floatx4){0.f, 0.f, 0.f, 0.f};
        acc = __builtin_amdgcn_mfma_f32_16x16x32_bf16(a0, b0, acc, 0, 0, 0);
        acc = __builtin_amdgcn_mfma_f32_16x16x32_bf16(a1, b1, acc, 0, 0, 0);
        const float bod = bo[n];
        #pragma unroll
        for (int r = 0; r < 4; r++)
            out[(row0 + quad * 4 + r) * 512 + n] = acc[r] + bod;
    }
}

extern "C" void kernel_launch(void* const* d_in, const int* in_sizes, int n_in,
                              void* d_out, int out_size, void* d_ws, size_t ws_size,
                              hipStream_t stream) {
    const float* x  = (const float*)d_in[0];
    const float* Wq = (const float*)d_in[1];
    const float* bq = (const float*)d_in[2];
    const float* Wk = (const float*)d_in[3];
    const float* bk = (const float*)d_in[4];
    const float* Wv = (const float*)d_in[5];
    const float* bv = (const float*)d_in[6];
    const float* Wo = (const float*)d_in[7];
    const float* bo = (const float*)d_in[8];
    float* out = (float*)d_out;

    unsigned short* Qb  = (unsigned short*)d_ws;               // 2 MB
    unsigned short* Kb  = Qb + (size_t)NROWS * 64;             // 2 MB
    unsigned short* Vt  = Kb + (size_t)NROWS * 64;             // 2 MB (transposed [b][64][s])
    unsigned short* WqT = Vt + (size_t)NROWS * 64;             // 64 KB each
    unsigned short* WkT = WqT + 512 * 64;
    unsigned short* WvT = WkT + 512 * 64;
    unsigned short* WoT = WvT + 512 * 64;
    float* Opart = (float*)(WoT + 512 * 64);                   // 2560 x 1024 fp32 = 10.5 MB
    float* lpart = Opart + (size_t)2560 * 1024;                // 2560 x 16 fp32

    convw_kernel<<<128, 256, 0, stream>>>(Wq, Wk, Wv, Wo, WqT, WkT, WvT, WoT);
    qkv_kernel<<<NROWS / 16, 64, 0, stream>>>(x, WqT, WkT, WvT, bq, bk, bv, Qb, Kb, Vt);
    attn_kernel<<<dim3(4, 4, 256), 256, 0, stream>>>(Qb, Kb, Vt, Opart, lpart);
    oproj_kernel<<<1024, 256, 0, stream>>>(Opart, lpart, WoT, bo, out);
}